// Round 17
// baseline (6700.081 us; speedup 1.0000x reference)
//
#include <hip/hip_runtime.h>

#define NB 32
#define NPTS 131072
#define KSAMP 2048
#define NPART 8
#define TPB 512
#define PART_PTS (NPTS / NPART)   // 16384
#define BATCH_F (NPTS * 3)
#define ZW_BYTES ((size_t)NB * NPTS * 4)          // 16 MB Z SoA
#define SLOT_OFF (ZW_BYTES)                       // slots after Zw

// R17: LDS-resident X/Y + L2-resident Z + coords-in-payload sync.
// Evidence: R10..R16 all ~4.6-4.9ms across AoS/SoA/float4/2-blocks-per-CU ->
// scan is L2-DELIVERY-BW bound (~200KB/CU/step ~ 1.5us floor). Fix: X,Y in
// 128KB LDS (ds_read_b128, 4 pts/inst, measured-fine stride), Z from 16MB
// SoA ws (2MB/XCD working set -> L2-resident). Winner coords travel through
// the sync payload (killing the dependent centroid fetch; also required
// since LDS slices are per-part).
//
// Numerics (bit-exact, validated R4/R10): d2 = fma(dz,dz,fma(dx,dx,dy*dy));
// md2 = fminf(md2,d2); ONE CR sqrt converts the thread winner to the ref sd
// domain; packed key (sd_bits<<32)|(131071-n) u64-max == jnp.argmax value +
// first-index. In-thread scan ascending n + strict > keeps first-index.
// Payload coords are bit-exact copies of the winner's stored coords.
//
// Sync: wave shfl argmax (carrying x,y,z) -> LDS -> wave0 cross-wave reduce
// -> lane0 publishes 3 tagged u64 slots {key, x|z_lo, y|z_hi} (agent relaxed
// stores) -> wave0 lanes 0..23 spin-read the 192B row until all 24 tags
// match -> reduce keys, shfl winner coords -> LDS broadcast -> barrier.
// Tags 1..2047 in bits 17..31 disambiguate 0xAA poison (0x5555) and stale
// replay data (deterministic => bitwise-identical anyway). Double-buffered
// rows kill WAR (proof: a part publishes k+2 only after exiting spin k+1,
// which requires every part to have published k+1, i.e. exited spin k).

#define GRP8(X) X(0)X(1)X(2)X(3)X(4)X(5)X(6)X(7)
#define RPT32(X) X(0)X(1)X(2)X(3)X(4)X(5)X(6)X(7)X(8)X(9)X(10)X(11)X(12) \
  X(13)X(14)X(15)X(16)X(17)X(18)X(19)X(20)X(21)X(22)X(23)X(24)X(25)X(26) \
  X(27)X(28)X(29)X(30)X(31)

__device__ __forceinline__ int read_start(const int* start, int b) {
  bool is64 = true;
  #pragma unroll 1
  for (int i = 1; i < 32; i += 2) {
    if (start[i] != 0) { is64 = false; break; }
  }
  return is64 ? start[2 * b] : start[b];
}

// ---------------- repack: Z -> SoA ----------------
__global__ __launch_bounds__(256) void repack_z(
    const float* __restrict__ x, float* __restrict__ Zw)
{
  const int blk = blockIdx.x;
  const int b   = blk >> 6;
  const int c   = blk & 63;
  const int t   = threadIdx.x;
  const float* xb = x + (size_t)b * BATCH_F;
  float* Zb = Zw + (size_t)b * NPTS;
  #pragma unroll
  for (int i = 0; i < 8; ++i) {
    const int n = c * 2048 + i * 256 + t;
    Zb[n] = xb[3 * n + 2];
  }
}

// ---------------- fps: LDS X/Y + SoA Z ----------------
__global__ __launch_bounds__(TPB) void fps_lds(
    const float* __restrict__ x, const float* __restrict__ Zw,
    const int* __restrict__ start, int* __restrict__ out,
    unsigned long long* __restrict__ slot)
{
  #pragma clang fp contract(off)
  const int blk  = blockIdx.x;
  const int xcd  = blk & 7;           // all 8 parts of a batch share an XCD
  const int j    = blk >> 3;
  const int b    = xcd * 4 + (j & 3);
  const int part = j >> 2;
  const int tid  = threadIdx.x;
  const int lane = tid & 63;
  const int wave = tid >> 6;

  const float* xb = x + (size_t)b * BATCH_F;   // AoS (init + start centroid)
  const float* Zb = Zw + (size_t)b * NPTS;     // SoA Z
  const int S = part * PART_PTS;

  __shared__ float Xl[PART_PTS];               // 64 KB
  __shared__ float Yl[PART_PTS];               // 64 KB
  __shared__ unsigned long long wkey[TPB / 64];
  __shared__ float wx[TPB / 64], wy[TPB / 64], wz[TPB / 64];
  __shared__ float bc[3];

  int cur = read_start(start, b);

  // LDS fill (one-time): thread owns q = g*2048 + tid*4 + i.
  #pragma unroll
  for (int g = 0; g < 8; ++g) {
    #pragma unroll
    for (int i = 0; i < 4; ++i) {
      const int q = g * 2048 + tid * 4 + i;
      const int n = S + q;
      Xl[q] = xb[3 * n + 0];
      Yl[q] = xb[3 * n + 1];
    }
  }

  #define DECLG(G) float md2_##G##_0 = __builtin_inff(),  \
      md2_##G##_1 = __builtin_inff(),                     \
      md2_##G##_2 = __builtin_inff(),                     \
      md2_##G##_3 = __builtin_inff();
  GRP8(DECLG)

  if (part == 0 && tid == 0) out[b * KSAMP] = cur;  // emit idx BEFORE update

  float cx = xb[3 * (size_t)cur + 0];
  float cy = xb[3 * (size_t)cur + 1];
  float cz = xb[3 * (size_t)cur + 2];

  // slot layout: [b][2][NPART][3] u64
  unsigned long long* const srow0 = slot + (size_t)b * 2 * NPART * 3;

  __syncthreads();   // LDS fill visible

  for (int k = 0; k < KSAMP - 1; ++k) {
    float bestv = -1.0f;   // d^2 domain
    int   bestn = 0;
    #define SC(G,I,XX,YY,ZZ) {                                  \
      const float dx = (XX) - cx;                               \
      const float dy = (YY) - cy;                               \
      const float dz = (ZZ) - cz;                               \
      const float d2 = fmaf(dz, dz, fmaf(dx, dx, dy * dy));     \
      const float m  = fminf(md2_##G##_##I, d2);                \
      md2_##G##_##I = m;                                        \
      if (m > bestv) { bestv = m; bestn = S + (G)*2048 + tid*4 + (I); } }
    #define SCANG(G) {                                                      \
      const float4 xv = *reinterpret_cast<const float4*>(&Xl[(G)*2048 + tid*4]); \
      const float4 yv = *reinterpret_cast<const float4*>(&Yl[(G)*2048 + tid*4]); \
      const float4 zv = *reinterpret_cast<const float4*>(Zb + S + (G)*2048 + tid*4); \
      SC(G,0,xv.x,yv.x,zv.x)                                                \
      SC(G,1,xv.y,yv.y,zv.y)                                                \
      SC(G,2,xv.z,yv.z,zv.z)                                                \
      SC(G,3,xv.w,yv.w,zv.w) }
    GRP8(SCANG)

    // Candidate coords (bit-exact stored values); issued before the reduce
    // so the global z load overlaps the shfl tree.
    const int bq = bestn - S;
    float cnx = Xl[bq];
    float cny = Yl[bq];
    float cnz = Zb[bestn];

    const float sdw = sqrtf(bestv);   // ONE CR sqrt -> ref sd domain
    unsigned long long key =
        ((unsigned long long)__float_as_uint(sdw) << 32) |
        (unsigned int)(NPTS - 1 - bestn);

    // wave argmax carrying coords
    #pragma unroll
    for (int off = 32; off >= 1; off >>= 1) {
      unsigned long long ok = __shfl_xor(key, off, 64);
      float ox = __shfl_xor(cnx, off, 64);
      float oy = __shfl_xor(cny, off, 64);
      float oz = __shfl_xor(cnz, off, 64);
      if (ok > key) { key = ok; cnx = ox; cny = oy; cnz = oz; }
    }
    if (lane == 0) {
      wkey[wave] = key; wx[wave] = cnx; wy[wave] = cny; wz[wave] = cnz;
    }
    __syncthreads();

    const unsigned tag = (unsigned)(k + 1);       // 1..2047
    unsigned long long* const row = srow0 + (unsigned)(k & 1) * (NPART * 3);

    if (wave == 0) {
      // cross-wave reduce (8 candidates, all aligned 8-groups identical)
      unsigned long long v = wkey[lane & 7];
      float fx = wx[lane & 7], fy = wy[lane & 7], fz = wz[lane & 7];
      #pragma unroll
      for (int off = 4; off >= 1; off >>= 1) {
        unsigned long long ok = __shfl_xor(v, off, 64);
        float ox = __shfl_xor(fx, off, 64);
        float oy = __shfl_xor(fy, off, 64);
        float oz = __shfl_xor(fz, off, 64);
        if (ok > v) { v = ok; fx = ox; fy = oy; fz = oz; }
      }

      if (lane == 0) {
        const unsigned zb = __float_as_uint(fz);
        const unsigned long long tg = (unsigned long long)tag << 17;
        unsigned long long A = v | tg;   // key bits17..31 are zero
        unsigned long long B = ((unsigned long long)__float_as_uint(fx) << 32)
                               | tg | (zb & 0x1FFFFu);
        unsigned long long C = ((unsigned long long)__float_as_uint(fy) << 32)
                               | tg | (zb >> 17);
        __hip_atomic_store(&row[part * 3 + 0], A, __ATOMIC_RELAXED,
                           __HIP_MEMORY_SCOPE_AGENT);
        __hip_atomic_store(&row[part * 3 + 1], B, __ATOMIC_RELAXED,
                           __HIP_MEMORY_SCOPE_AGENT);
        __hip_atomic_store(&row[part * 3 + 2], C, __ATOMIC_RELAXED,
                           __HIP_MEMORY_SCOPE_AGENT);
      }

      // lanes 0..23 poll the 24 u64 row: lane l -> part (l&7), slot (l>>3)
      const int pidx = (lane < 24) ? ((lane & 7) * 3 + (lane >> 3)) : 0;
      unsigned long long g;
      do {
        g = __hip_atomic_load(&row[pidx], __ATOMIC_RELAXED,
                              __HIP_MEMORY_SCOPE_AGENT);
      } while (__ballot(lane >= 24 ||
                        (((unsigned)(g >> 17) & 0x7FFFu) == tag)) != ~0ull);

      // reduce keys (lanes 0..7 hold A slots; tags equal so raw compare ok)
      unsigned long long kk = (lane < 8) ? g : 0ull;
      #pragma unroll
      for (int off = 4; off >= 1; off >>= 1) {
        unsigned long long o = __shfl_xor(kk, off, 64);
        if (o > kk) kk = o;
      }
      const unsigned long long bk = __shfl(kk, 0, 64);
      const unsigned long long mask = __ballot(lane < 8 && g == bk);
      const int w = __ffsll((unsigned long long)mask) - 1;

      const unsigned long long Bw = __shfl(g, 8 + w, 64);
      const unsigned long long Cw = __shfl(g, 16 + w, 64);
      const unsigned zbits = (unsigned)(Bw & 0x1FFFFu) |
                             ((unsigned)(Cw & 0x7FFFu) << 17);
      if (lane == 0) {
        bc[0] = __uint_as_float((unsigned)(Bw >> 32));
        bc[1] = __uint_as_float((unsigned)(Cw >> 32));
        bc[2] = __uint_as_float(zbits);
        if (part == 0)
          out[b * KSAMP + k + 1] = NPTS - 1 - (int)(bk & 0x1FFFFu);
      }
    }
    __syncthreads();

    cx = bc[0];
    cy = bc[1];
    cz = bc[2];
  }
}

// ---------------- fallback: R10 AoS (proven) ----------------
__global__ __launch_bounds__(TPB)
__attribute__((amdgpu_waves_per_eu(2, 2)))
void fps_aos(
    const float* __restrict__ x, const int* __restrict__ start,
    int* __restrict__ out, unsigned long long* __restrict__ slot)
{
  #pragma clang fp contract(off)
  const int blk  = blockIdx.x;
  const int xcd  = blk & 7;
  const int j    = blk >> 3;
  const int b    = xcd * 4 + (j & 3);
  const int part = j >> 2;
  const int tid  = threadIdx.x;
  const int lane = tid & 63;
  const int wave = tid >> 6;

  const float* xb = x + (size_t)b * BATCH_F;
  int cur = read_start(start, b);
  const int base = part * PART_PTS + tid;

  #define DECLP(J) float px##J, py##J, pz##J, md2##J;
  RPT32(DECLP)
  #define INITP(J) { const int n = base + (J) * TPB;          \
      px##J = xb[3*n]; py##J = xb[3*n+1]; pz##J = xb[3*n+2];  \
      md2##J = __builtin_inff(); }
  RPT32(INITP)

  __shared__ unsigned long long wred[TPB / 64];
  __shared__ int snext;

  if (part == 0 && tid == 0) out[b * KSAMP] = cur;

  float cx = xb[3 * (size_t)cur + 0];
  float cy = xb[3 * (size_t)cur + 1];
  float cz = xb[3 * (size_t)cur + 2];

  unsigned long long* const srow0 = slot + (size_t)b * 2 * NPART;

  for (int k = 0; k < KSAMP - 1; ++k) {
    float bestv = -1.0f;
    int   bestn = 0;
    #define SCANP(J) {                                              \
      const float dx = px##J - cx;                                  \
      const float dy = py##J - cy;                                  \
      const float dz = pz##J - cz;                                  \
      const float d2 = fmaf(dz, dz, fmaf(dx, dx, dy * dy));         \
      const float m  = fminf(md2##J, d2);                           \
      md2##J = m;                                                   \
      if (m > bestv) { bestv = m; bestn = base + (J) * TPB; }       \
    }
    RPT32(SCANP)

    const float sdw = sqrtf(bestv);
    unsigned long long key =
        ((unsigned long long)__float_as_uint(sdw) << 32) |
        (unsigned int)(NPTS - 1 - bestn);

    #pragma unroll
    for (int off = 32; off >= 1; off >>= 1) {
      unsigned long long o = __shfl_xor(key, off, 64);
      if (o > key) key = o;
    }
    if (lane == 0) wred[wave] = key;
    __syncthreads();

    if (wave == 0) {
      unsigned long long v = wred[lane & 7];
      #pragma unroll
      for (int off = 4; off >= 1; off >>= 1) {
        unsigned long long o = __shfl_xor(v, off, 64);
        if (o > v) v = o;
      }
      const unsigned tag = (unsigned)(k + 1);
      unsigned long long* const row = srow0 + (unsigned)(k & 1) * NPART;
      if (lane == 0)
        __hip_atomic_store(&row[part], v | ((unsigned long long)tag << 17),
                           __ATOMIC_RELAXED, __HIP_MEMORY_SCOPE_AGENT);

      unsigned long long g;
      do {
        g = __hip_atomic_load(&row[lane & (NPART - 1)], __ATOMIC_RELAXED,
                              __HIP_MEMORY_SCOPE_AGENT);
      } while (__ballot(((unsigned)(g >> 17) & 0x7FFFu) == tag) != ~0ull);

      #pragma unroll
      for (int off = 4; off >= 1; off >>= 1) {
        unsigned long long o = __shfl_xor(g, off, 64);
        if (o > g) g = o;
      }
      const int nidx = NPTS - 1 - (int)(g & 0x1FFFFu);
      if (lane == 0) {
        snext = nidx;
        if (part == 0) out[b * KSAMP + k + 1] = nidx;
      }
    }
    __syncthreads();

    const int nidx = snext;
    cx = xb[3 * (size_t)nidx + 0];
    cy = xb[3 * (size_t)nidx + 1];
    cz = xb[3 * (size_t)nidx + 2];
  }
}

extern "C" void kernel_launch(void* const* d_in, const int* in_sizes, int n_in,
                              void* d_out, int out_size, void* d_ws, size_t ws_size,
                              hipStream_t stream) {
  const float* x     = (const float*)d_in[0];
  const int*   start = (const int*)d_in[1];
  int*         out   = (int*)d_out;

  if (ws_size >= ZW_BYTES + 16384) {
    float* Zw = (float*)d_ws;
    unsigned long long* slot = (unsigned long long*)((char*)d_ws + SLOT_OFF);
    repack_z<<<dim3(NB * 64), dim3(256), 0, stream>>>(x, Zw);
    void* args[] = {(void*)&x, (void*)&Zw, (void*)&start, (void*)&out,
                    (void*)&slot};
    hipLaunchCooperativeKernel((void*)fps_lds, dim3(NB * NPART), dim3(TPB),
                               args, 0, stream);
  } else {
    unsigned long long* slot = (unsigned long long*)d_ws;
    void* args[] = {(void*)&x, (void*)&start, (void*)&out, (void*)&slot};
    hipLaunchCooperativeKernel((void*)fps_aos, dim3(NB * NPART), dim3(TPB),
                               args, 0, stream);
  }
}

// Round 18
// 4936.388 us; speedup vs baseline: 1.3573x; 1.3573x over previous
//
#include <hip/hip_runtime.h>

#define NB 32
#define NPTS 131072
#define KSAMP 2048
#define NPART 8
#define TPB 512
#define PART_PTS (NPTS / NPART)   // 16384
#define BATCH_F (NPTS * 3)
#define ZW_BYTES ((size_t)NB * NPTS * 4)          // 16 MB Z SoA
#define SLOT_OFF (ZW_BYTES)

// R18 = R17 data path + R10 lean sync.
// Model (R10/R14/R16/R17 counters): scan is per-CU L2-delivery bound
// (196KB/CU/step at ~86GB/s/CU ~ 1.5us); VALU-busy is a constant 1.38us/step
// and not binding; 2-blocks/CU overlap doesn't help (throughput wall).
// Fix: X,Y (128KB) live in LDS at 307GB/s; Z (64KB/CU/step) streams from a
// SoA workspace whose per-XCD working set (2MB) is L2-resident. The sync
// stays R10's proven minimal form: single tagged key slot per part, wave0
// 8-lane spin, snext LDS broadcast, centroid = 3 AoS scalar loads (L2/L3).
// R17's payload-sync (3 slots, 24-lane spin, 4-value shfl trees) added
// ~1us/step of serial cost and is reverted.
//
// Numerics (bit-exact validated R4/R10): d2 = fma(dz,dz,fma(dx,dx,dy*dy));
// md2 = fminf(md2,d2); ONE CR sqrt converts the thread winner to the ref sd
// domain (CR-sqrt monotone); key (sd_bits<<32)|(131071-n) u64-max ==
// jnp.argmax value+first-index. In-thread ascending n + strict >.
//
// Sync (R6/R10-proven): wave shfl max -> LDS -> wave0 cross-wave max ->
// tagged publish (agent relaxed store) -> wave0 spins on 64B row until all
// 8 tags match -> LDS broadcast -> barrier. Tags 1..2047 disambiguate 0xAA
// poison (0x5555) / stale replay data; double-buffered rows kill WAR.

#define GRP8(X) X(0)X(1)X(2)X(3)X(4)X(5)X(6)X(7)
#define RPT32(X) X(0)X(1)X(2)X(3)X(4)X(5)X(6)X(7)X(8)X(9)X(10)X(11)X(12) \
  X(13)X(14)X(15)X(16)X(17)X(18)X(19)X(20)X(21)X(22)X(23)X(24)X(25)X(26) \
  X(27)X(28)X(29)X(30)X(31)

__device__ __forceinline__ int read_start(const int* start, int b) {
  bool is64 = true;
  #pragma unroll 1
  for (int i = 1; i < 32; i += 2) {
    if (start[i] != 0) { is64 = false; break; }
  }
  return is64 ? start[2 * b] : start[b];
}

// ---------------- repack: Z -> SoA ----------------
__global__ __launch_bounds__(256) void repack_z(
    const float* __restrict__ x, float* __restrict__ Zw)
{
  const int blk = blockIdx.x;
  const int b   = blk >> 6;
  const int c   = blk & 63;
  const int t   = threadIdx.x;
  const float* xb = x + (size_t)b * BATCH_F;
  float* Zb = Zw + (size_t)b * NPTS;
  #pragma unroll
  for (int i = 0; i < 8; ++i) {
    const int n = c * 2048 + i * 256 + t;
    Zb[n] = xb[3 * n + 2];
  }
}

// ---------------- fps: LDS X/Y + L2 Z, lean sync ----------------
__global__ __launch_bounds__(TPB) void fps_lds(
    const float* __restrict__ x, const float* __restrict__ Zw,
    const int* __restrict__ start, int* __restrict__ out,
    unsigned long long* __restrict__ slot)
{
  #pragma clang fp contract(off)
  const int blk  = blockIdx.x;
  const int xcd  = blk & 7;           // parts of a batch share an XCD
  const int j    = blk >> 3;
  const int b    = xcd * 4 + (j & 3);
  const int part = j >> 2;
  const int tid  = threadIdx.x;
  const int lane = tid & 63;
  const int wave = tid >> 6;

  const float* xb = x + (size_t)b * BATCH_F;   // AoS (init + centroid fetch)
  const float* Zb = Zw + (size_t)b * NPTS;     // SoA Z (L2-resident slice)
  const int S = part * PART_PTS;

  __shared__ float Xl[PART_PTS];               // 64 KB
  __shared__ float Yl[PART_PTS];               // 64 KB
  __shared__ unsigned long long wred[TPB / 64];
  __shared__ int snext;

  int cur = read_start(start, b);

  // LDS fill (one-time): thread owns q = g*2048 + tid*4 + i.
  #pragma unroll
  for (int g = 0; g < 8; ++g) {
    #pragma unroll
    for (int i = 0; i < 4; ++i) {
      const int q = g * 2048 + tid * 4 + i;
      const int n = S + q;
      Xl[q] = xb[3 * n + 0];
      Yl[q] = xb[3 * n + 1];
    }
  }

  #define DECLG(G) float md2_##G##_0 = __builtin_inff(),  \
      md2_##G##_1 = __builtin_inff(),                     \
      md2_##G##_2 = __builtin_inff(),                     \
      md2_##G##_3 = __builtin_inff();
  GRP8(DECLG)

  if (part == 0 && tid == 0) out[b * KSAMP] = cur;  // emit idx BEFORE update

  float cx = xb[3 * (size_t)cur + 0];
  float cy = xb[3 * (size_t)cur + 1];
  float cz = xb[3 * (size_t)cur + 2];

  unsigned long long* const srow0 = slot + (size_t)b * 2 * NPART;  // [b][2][8]

  __syncthreads();   // LDS fill visible

  for (int k = 0; k < KSAMP - 1; ++k) {
    float bestv = -1.0f;   // d^2 domain
    int   bestn = 0;
    #define SC(G,I,XX,YY,ZZ) {                                  \
      const float dx = (XX) - cx;                               \
      const float dy = (YY) - cy;                               \
      const float dz = (ZZ) - cz;                               \
      const float d2 = fmaf(dz, dz, fmaf(dx, dx, dy * dy));     \
      const float m  = fminf(md2_##G##_##I, d2);                \
      md2_##G##_##I = m;                                        \
      if (m > bestv) { bestv = m; bestn = S + (G)*2048 + tid*4 + (I); } }
    #define SCANG(G) {                                                      \
      const float4 xv = *reinterpret_cast<const float4*>(&Xl[(G)*2048 + tid*4]); \
      const float4 yv = *reinterpret_cast<const float4*>(&Yl[(G)*2048 + tid*4]); \
      const float4 zv = *reinterpret_cast<const float4*>(Zb + S + (G)*2048 + tid*4); \
      SC(G,0,xv.x,yv.x,zv.x)                                                \
      SC(G,1,xv.y,yv.y,zv.y)                                                \
      SC(G,2,xv.z,yv.z,zv.z)                                                \
      SC(G,3,xv.w,yv.w,zv.w) }
    GRP8(SCANG)

    const float sdw = sqrtf(bestv);   // ONE CR sqrt -> ref sd domain
    unsigned long long key =
        ((unsigned long long)__float_as_uint(sdw) << 32) |
        (unsigned int)(NPTS - 1 - bestn);

    #pragma unroll
    for (int off = 32; off >= 1; off >>= 1) {
      unsigned long long o = __shfl_xor(key, off, 64);
      if (o > key) key = o;
    }
    if (lane == 0) wred[wave] = key;
    __syncthreads();

    if (wave == 0) {
      unsigned long long v = wred[lane & 7];
      #pragma unroll
      for (int off = 4; off >= 1; off >>= 1) {
        unsigned long long o = __shfl_xor(v, off, 64);
        if (o > v) v = o;
      }

      const unsigned tag = (unsigned)(k + 1);     // 1..2047
      unsigned long long* const row = srow0 + (unsigned)(k & 1) * NPART;
      if (lane == 0)
        __hip_atomic_store(&row[part], v | ((unsigned long long)tag << 17),
                           __ATOMIC_RELAXED, __HIP_MEMORY_SCOPE_AGENT);

      unsigned long long g;
      do {
        g = __hip_atomic_load(&row[lane & (NPART - 1)], __ATOMIC_RELAXED,
                              __HIP_MEMORY_SCOPE_AGENT);
      } while (__ballot(((unsigned)(g >> 17) & 0x7FFFu) == tag) != ~0ull);

      #pragma unroll
      for (int off = 4; off >= 1; off >>= 1) {
        unsigned long long o = __shfl_xor(g, off, 64);
        if (o > g) g = o;
      }
      const int nidx = NPTS - 1 - (int)(g & 0x1FFFFu);
      if (lane == 0) {
        snext = nidx;
        if (part == 0) out[b * KSAMP + k + 1] = nidx;
      }
    }
    __syncthreads();

    const int nidx = snext;
    cx = xb[3 * (size_t)nidx + 0];
    cy = xb[3 * (size_t)nidx + 1];
    cz = xb[3 * (size_t)nidx + 2];
  }
}

// ---------------- fallback: R10 AoS (proven) ----------------
__global__ __launch_bounds__(TPB)
__attribute__((amdgpu_waves_per_eu(2, 2)))
void fps_aos(
    const float* __restrict__ x, const int* __restrict__ start,
    int* __restrict__ out, unsigned long long* __restrict__ slot)
{
  #pragma clang fp contract(off)
  const int blk  = blockIdx.x;
  const int xcd  = blk & 7;
  const int j    = blk >> 3;
  const int b    = xcd * 4 + (j & 3);
  const int part = j >> 2;
  const int tid  = threadIdx.x;
  const int lane = tid & 63;
  const int wave = tid >> 6;

  const float* xb = x + (size_t)b * BATCH_F;
  int cur = read_start(start, b);
  const int base = part * PART_PTS + tid;

  #define DECLP(J) float px##J, py##J, pz##J, md2##J;
  RPT32(DECLP)
  #define INITP(J) { const int n = base + (J) * TPB;          \
      px##J = xb[3*n]; py##J = xb[3*n+1]; pz##J = xb[3*n+2];  \
      md2##J = __builtin_inff(); }
  RPT32(INITP)

  __shared__ unsigned long long wred[TPB / 64];
  __shared__ int snext;

  if (part == 0 && tid == 0) out[b * KSAMP] = cur;

  float cx = xb[3 * (size_t)cur + 0];
  float cy = xb[3 * (size_t)cur + 1];
  float cz = xb[3 * (size_t)cur + 2];

  unsigned long long* const srow0 = slot + (size_t)b * 2 * NPART;

  for (int k = 0; k < KSAMP - 1; ++k) {
    float bestv = -1.0f;
    int   bestn = 0;
    #define SCANP(J) {                                              \
      const float dx = px##J - cx;                                  \
      const float dy = py##J - cy;                                  \
      const float dz = pz##J - cz;                                  \
      const float d2 = fmaf(dz, dz, fmaf(dx, dx, dy * dy));         \
      const float m  = fminf(md2##J, d2);                           \
      md2##J = m;                                                   \
      if (m > bestv) { bestv = m; bestn = base + (J) * TPB; }       \
    }
    RPT32(SCANP)

    const float sdw = sqrtf(bestv);
    unsigned long long key =
        ((unsigned long long)__float_as_uint(sdw) << 32) |
        (unsigned int)(NPTS - 1 - bestn);

    #pragma unroll
    for (int off = 32; off >= 1; off >>= 1) {
      unsigned long long o = __shfl_xor(key, off, 64);
      if (o > key) key = o;
    }
    if (lane == 0) wred[wave] = key;
    __syncthreads();

    if (wave == 0) {
      unsigned long long v = wred[lane & 7];
      #pragma unroll
      for (int off = 4; off >= 1; off >>= 1) {
        unsigned long long o = __shfl_xor(v, off, 64);
        if (o > v) v = o;
      }
      const unsigned tag = (unsigned)(k + 1);
      unsigned long long* const row = srow0 + (unsigned)(k & 1) * NPART;
      if (lane == 0)
        __hip_atomic_store(&row[part], v | ((unsigned long long)tag << 17),
                           __ATOMIC_RELAXED, __HIP_MEMORY_SCOPE_AGENT);

      unsigned long long g;
      do {
        g = __hip_atomic_load(&row[lane & (NPART - 1)], __ATOMIC_RELAXED,
                              __HIP_MEMORY_SCOPE_AGENT);
      } while (__ballot(((unsigned)(g >> 17) & 0x7FFFu) == tag) != ~0ull);

      #pragma unroll
      for (int off = 4; off >= 1; off >>= 1) {
        unsigned long long o = __shfl_xor(g, off, 64);
        if (o > g) g = o;
      }
      const int nidx = NPTS - 1 - (int)(g & 0x1FFFFu);
      if (lane == 0) {
        snext = nidx;
        if (part == 0) out[b * KSAMP + k + 1] = nidx;
      }
    }
    __syncthreads();

    const int nidx = snext;
    cx = xb[3 * (size_t)nidx + 0];
    cy = xb[3 * (size_t)nidx + 1];
    cz = xb[3 * (size_t)nidx + 2];
  }
}

extern "C" void kernel_launch(void* const* d_in, const int* in_sizes, int n_in,
                              void* d_out, int out_size, void* d_ws, size_t ws_size,
                              hipStream_t stream) {
  const float* x     = (const float*)d_in[0];
  const int*   start = (const int*)d_in[1];
  int*         out   = (int*)d_out;

  if (ws_size >= ZW_BYTES + 16384) {
    float* Zw = (float*)d_ws;
    unsigned long long* slot = (unsigned long long*)((char*)d_ws + SLOT_OFF);
    repack_z<<<dim3(NB * 64), dim3(256), 0, stream>>>(x, Zw);
    void* args[] = {(void*)&x, (void*)&Zw, (void*)&start, (void*)&out,
                    (void*)&slot};
    hipLaunchCooperativeKernel((void*)fps_lds, dim3(NB * NPART), dim3(TPB),
                               args, 0, stream);
  } else {
    unsigned long long* slot = (unsigned long long*)d_ws;
    void* args[] = {(void*)&x, (void*)&start, (void*)&out, (void*)&slot};
    hipLaunchCooperativeKernel((void*)fps_aos, dim3(NB * NPART), dim3(TPB),
                               args, 0, stream);
  }
}